// Round 15
// baseline (502.293 us; speedup 1.0000x reference)
//
#include <hip/hip_runtime.h>
#include <cstdint>
#include <cstddef>

#define S_LEN 250
#define BATCH 256
#define CIN   700
#define HID   256
#define OUT_N 20
#define KSTEPS 22   // ceil(700/32); 22*32 = 704 (W prepped zero-padded)
#define KPAD  704

typedef __attribute__((ext_vector_type(8))) short bf16x8;
typedef __attribute__((ext_vector_type(8))) unsigned short u16x8;
typedef __attribute__((ext_vector_type(4))) float f32x4;

__device__ __forceinline__ ushort f2bf_rne(float f) {
    uint u = __float_as_uint(f);
    uint r = (u + 0x7FFFu + ((u >> 16) & 1u)) >> 16;
    return (ushort)r;
}
__device__ __forceinline__ float bf2f(ushort h) {
    return __uint_as_float(((uint)h) << 16);
}

// ---------------------------------------------------------------------------
// Kernel 0: one-shot W_in hi/lo bf16 prep, transposed to [col][k] (k padded
// to 704 with zeros). Same f2bf_rne on same inputs as the in-loop path ->
// downstream P is bit-identical.
// ---------------------------------------------------------------------------
__global__ __launch_bounds__(512) void w_prep(
    const float* __restrict__ Wf, const float* __restrict__ Wb,
    ushort* __restrict__ Wth, ushort* __restrict__ Wtl)
{
    const int k = blockIdx.x;       // 0..703
    const int c = threadIdx.x;      // 0..511 (fw cols 0-255, bw cols 256-511)
    float v = 0.f;
    if (k < CIN)
        v = (c < HID) ? Wf[(size_t)k * HID + c]
                      : Wb[(size_t)k * HID + (c - HID)];
    const ushort h = f2bf_rne(v);
    const ushort l = f2bf_rne(__fsub_rn(v, bf2f(h)));
    Wth[(size_t)c * KPAD + k] = h;
    Wtl[(size_t)c * KPAD + k] = l;
}

// ---------------------------------------------------------------------------
// Kernel 1: input projection GEMM via bf16x3 split MFMA.
// Grid (2 dirs, 500 m-tiles); each block computes all 256 cols of one dir.
// PREW=true: B staged from pre-converted hi/lo bf16 (8 ushort8 loads, zero
// conversion VALU). PREW=false: R14 in-loop convert fallback.
// Arithmetic identical per output element -> bit-identical P vs R14.
// ---------------------------------------------------------------------------
template<bool PREW>
__global__ __launch_bounds__(256) void proj_mfma(
    const float* __restrict__ x,
    const float* __restrict__ Wf, const float* __restrict__ Wb,
    const float* __restrict__ biasf, const float* __restrict__ biasb,
    const ushort* __restrict__ Wth, const ushort* __restrict__ Wtl,
    float* __restrict__ P)
{
    __shared__ ushort AsH[128][40];
    __shared__ ushort AsL[128][40];
    __shared__ ushort BsH[256][40];
    __shared__ ushort BsL[256][40];

    const int nt = blockIdx.x;          // 0 = fw cols, 1 = bw cols
    const int mt = blockIdx.y;          // 0..499
    const int m0 = mt * 128;
    const float* W   = nt ? Wb : Wf;
    const float* bia = nt ? biasb : biasf;

    const int tid  = threadIdx.x;
    const int lane = tid & 63;
    const int wv   = tid >> 6;          // wave 0..3
    const int wr   = wv >> 1;           // row-half
    const int wc   = wv & 1;            // col-half (128 cols each)
    const int l15  = lane & 15;
    const int l4   = lane >> 4;

    const int as  = tid & 7;            // A k-slot (4 floats)
    const int arr = tid >> 3;           // A row 0..31 (x4 row-groups)

    f32x4 acc[4][8];
#pragma unroll
    for (int i = 0; i < 4; i++)
#pragma unroll
        for (int j = 0; j < 8; j++)
            acc[i][j] = (f32x4){0.f, 0.f, 0.f, 0.f};

    float4 av[4];
    float bv[32];                       // !PREW only
    u16x8 bh[4], bl[4];                 // PREW only

    auto LOADT = [&](int K0) {
        const int ka = K0 + as * 4;
        const bool aok = (ka + 3) < CIN;
#pragma unroll
        for (int i = 0; i < 4; i++) {
            av[i] = make_float4(0.f, 0.f, 0.f, 0.f);
            if (aok)
                av[i] = *(const float4*)&x[(size_t)(m0 + arr + 32 * i) * CIN + ka];
        }
        if constexpr (PREW) {
            const size_t base = (size_t)(nt * HID + tid) * KPAD + K0;
#pragma unroll
            for (int q = 0; q < 4; q++) {
                bh[q] = *(const u16x8*)&Wth[base + q * 8];
                bl[q] = *(const u16x8*)&Wtl[base + q * 8];
            }
        } else {
#pragma unroll
            for (int j = 0; j < 32; j++) {
                const int kb = K0 + j;
                bv[j] = (kb < CIN) ? W[(size_t)kb * HID + tid] : 0.f;
            }
        }
    };

    auto WRITET = [&]() {
#pragma unroll
        for (int i = 0; i < 4; i++) {
            const int row = arr + 32 * i;
            ushort4 h, l;
            h.x = f2bf_rne(av[i].x); l.x = f2bf_rne(__fsub_rn(av[i].x, bf2f(h.x)));
            h.y = f2bf_rne(av[i].y); l.y = f2bf_rne(__fsub_rn(av[i].y, bf2f(h.y)));
            h.z = f2bf_rne(av[i].z); l.z = f2bf_rne(__fsub_rn(av[i].z, bf2f(h.z)));
            h.w = f2bf_rne(av[i].w); l.w = f2bf_rne(__fsub_rn(av[i].w, bf2f(h.w)));
            *(ushort4*)&AsH[row][as * 4] = h;
            *(ushort4*)&AsL[row][as * 4] = l;
        }
        if constexpr (PREW) {
#pragma unroll
            for (int q = 0; q < 4; q++) {
                *(u16x8*)&BsH[tid][q * 8] = bh[q];
                *(u16x8*)&BsL[tid][q * 8] = bl[q];
            }
        } else {
#pragma unroll
            for (int q = 0; q < 8; q++) {
                ushort4 h, l;
                float v0 = bv[q * 4 + 0], v1 = bv[q * 4 + 1];
                float v2 = bv[q * 4 + 2], v3 = bv[q * 4 + 3];
                h.x = f2bf_rne(v0); l.x = f2bf_rne(__fsub_rn(v0, bf2f(h.x)));
                h.y = f2bf_rne(v1); l.y = f2bf_rne(__fsub_rn(v1, bf2f(h.y)));
                h.z = f2bf_rne(v2); l.z = f2bf_rne(__fsub_rn(v2, bf2f(h.z)));
                h.w = f2bf_rne(v3); l.w = f2bf_rne(__fsub_rn(v3, bf2f(h.w)));
                *(ushort4*)&BsH[tid][q * 4] = h;
                *(ushort4*)&BsL[tid][q * 4] = l;
            }
        }
    };

    LOADT(0);
    WRITET();

    for (int kt = 0; kt < KSTEPS; kt++) {
        __syncthreads();                 // tile kt writes visible
        if (kt + 1 < KSTEPS)
            LOADT((kt + 1) * 32);        // next loads land during MFMA

#pragma unroll
        for (int fc = 0; fc < 8; fc++) {
            const bf16x8 bHf = *(const bf16x8*)&BsH[wc * 128 + fc * 16 + l15][l4 * 8];
            const bf16x8 bLf = *(const bf16x8*)&BsL[wc * 128 + fc * 16 + l15][l4 * 8];
#pragma unroll
            for (int fr = 0; fr < 4; fr++) {
                const bf16x8 aHf = *(const bf16x8*)&AsH[wr * 64 + fr * 16 + l15][l4 * 8];
                const bf16x8 aLf = *(const bf16x8*)&AsL[wr * 64 + fr * 16 + l15][l4 * 8];
                acc[fr][fc] = __builtin_amdgcn_mfma_f32_16x16x32_bf16(
                    aHf, bHf, acc[fr][fc], 0, 0, 0);
                acc[fr][fc] = __builtin_amdgcn_mfma_f32_16x16x32_bf16(
                    aHf, bLf, acc[fr][fc], 0, 0, 0);
                acc[fr][fc] = __builtin_amdgcn_mfma_f32_16x16x32_bf16(
                    aLf, bHf, acc[fr][fc], 0, 0, 0);
            }
        }

        __syncthreads();                 // all reads of tile kt done
        if (kt + 1 < KSTEPS)
            WRITET();
    }

#pragma unroll
    for (int fc = 0; fc < 8; fc++) {
        const int col = wc * 128 + fc * 16 + l15;      // 0..255 in direction
        const float bvs = bia[col];
#pragma unroll
        for (int fr = 0; fr < 4; fr++) {
#pragma unroll
            for (int j = 0; j < 4; j++) {
                const int row = m0 + wr * 64 + fr * 16 + l4 * 4 + j;
                P[(size_t)row * 512 + nt * HID + col] =
                    __fadd_rn(acc[fr][fc][j], bvs);
            }
        }
    }
}

// ---------------------------------------------------------------------------
// Kernel 2: MFMA scan — EXACT R6 form (best measured: 293-294us, absmax
// 0.0625). All timing micro-variants (R9/R10/R13) measured neutral-or-worse;
// counters show ~76% MFMA+VALU issue-busy on active CUs = structural optimum
// for this decomposition. FROZEN.
// ---------------------------------------------------------------------------
__global__ __launch_bounds__(512, 2) void scan_mfma(
    const float* __restrict__ P,
    const float* __restrict__ Wrecf, const float* __restrict__ brecf,
    const float* __restrict__ taumf, const float* __restrict__ tauaf,
    const float* __restrict__ Wrecb, const float* __restrict__ brecb,
    const float* __restrict__ taumb, const float* __restrict__ tauab,
    const float* __restrict__ Wout, const float* __restrict__ taumo,
    float* __restrict__ Pst)
{
    const int g  = blockIdx.x;          // batch group: b0..b0+15
    const int d  = blockIdx.y;          // 0 = fw, 1 = bw
    const int b0 = g * 16;
    const bool fw = (d == 0);

    const int tid  = threadIdx.x;
    const int lane = tid & 63;
    const int w    = tid >> 6;          // wave 0..7
    const int l15  = lane & 15;
    const int l4   = lane >> 4;

    __shared__ ushort Sp[2][16][264];   // [buf][batch][col(+pad)] bf16 spikes

    {   // zero both spike buffers (step -1 spikes = 0)
        ushort* p = &Sp[0][0][0];
        for (int i = tid; i < 2 * 16 * 264; i += 512) p[i] = 0;
    }

    const float* Wrec = fw ? Wrecf : Wrecb;

    // ---- W_rec fragments (hi+lo bf16), register resident
    bf16x8 whf[8][2], wlf[8][2];
#pragma unroll
    for (int kt = 0; kt < 8; kt++)
#pragma unroll
        for (int ct = 0; ct < 2; ct++) {
            const int c = w * 32 + ct * 16 + l15;
#pragma unroll
            for (int j = 0; j < 8; j++) {
                const float v = Wrec[(size_t)(kt * 32 + l4 * 8 + j) * HID + c];
                const ushort h = f2bf_rne(v);
                const ushort l = f2bf_rne(__fsub_rn(v, bf2f(h)));
                whf[kt][ct][j] = (short)h;
                wlf[kt][ct][j] = (short)l;
            }
        }

    // ---- W_out fragments for this wave's 32-k slice (hi+lo)
    bf16x8 woh[2], wol[2];
#pragma unroll
    for (int t = 0; t < 2; t++) {
        const int o = t * 16 + l15;
#pragma unroll
        for (int j = 0; j < 8; j++) {
            float v = 0.f;
            if (o < OUT_N)
                v = Wout[(size_t)(d * HID + w * 32 + l4 * 8 + j) * OUT_N + o];
            const ushort h = f2bf_rne(v);
            const ushort l = f2bf_rne(__fsub_rn(v, bf2f(h)));
            woh[t][j] = (short)h;
            wol[t][j] = (short)l;
        }
    }

    // ---- LIF constants for this thread's 2 columns
    float alpha_[2], ro_[2], omA_[2], omR_[2], brc_[2];
#pragma unroll
    for (int t = 0; t < 2; t++) {
        const int c = w * 32 + t * 16 + l15;
        alpha_[t] = expf(__fdiv_rn(-1.f, fw ? taumf[c] : taumb[c]));
        ro_[t]    = expf(__fdiv_rn(-1.f, fw ? tauaf[c] : tauab[c]));
        omA_[t]   = __fsub_rn(1.f, alpha_[t]);
        omR_[t]   = __fsub_rn(1.f, ro_[t]);
        brc_[t]   = fw ? brecf[c] : brecb[c];
    }
    // ---- readout constants
    float ao_[2], omo_[2];
#pragma unroll
    for (int t = 0; t < 2; t++) {
        const int o = t * 16 + l15;
        if (o < OUT_N) {
            ao_[t]  = expf(__fdiv_rn(-1.f, taumo[o]));
            omo_[t] = __fsub_rn(1.f, ao_[t]);
        } else { ao_[t] = 0.f; omo_[t] = 0.f; }
    }

    float mem[2][4], bbv[2][4], spkv[2][4], z[2][4];
#pragma unroll
    for (int t = 0; t < 2; t++)
#pragma unroll
        for (int j = 0; j < 4; j++) {
            mem[t][j] = 0.f; bbv[t][j] = 0.01f; spkv[t][j] = 0.f; z[t][j] = 0.f;
        }

    // pv prefetch for s=0
    float pv[2][4];
    {
        const int srow = fw ? 0 : (S_LEN - 1);
#pragma unroll
        for (int t = 0; t < 2; t++)
#pragma unroll
            for (int j = 0; j < 4; j++)
                pv[t][j] = P[((size_t)(b0 + l4 * 4 + j) * S_LEN + srow) * 512
                             + d * HID + w * 32 + t * 16 + l15];
    }

    for (int s = 0; s < S_LEN; s++) {
        const int cur = s & 1, prev = cur ^ 1;

        // prefetch next step's projection BEFORE the barrier (R6 exact)
        float pv_next[2][4];
        {
            const int sn   = (s + 1 < S_LEN) ? s + 1 : S_LEN - 1;
            const int srow = fw ? sn : (S_LEN - 1 - sn);
#pragma unroll
            for (int t = 0; t < 2; t++)
#pragma unroll
                for (int j = 0; j < 4; j++)
                    pv_next[t][j] = P[((size_t)(b0 + l4 * 4 + j) * S_LEN + srow) * 512
                                      + d * HID + w * 32 + t * 16 + l15];
        }

        __syncthreads();   // Sp[prev] complete from all waves

        // ---- recurrent GEMM: D[batch][col] += spk(prev) @ W_rec
        f32x4 acc[2];
        acc[0] = (f32x4){0.f, 0.f, 0.f, 0.f};
        acc[1] = (f32x4){0.f, 0.f, 0.f, 0.f};
#pragma unroll
        for (int kt = 0; kt < 8; kt++) {
            const bf16x8 a = *(const bf16x8*)&Sp[prev][l15][kt * 32 + l4 * 8];
            acc[0] = __builtin_amdgcn_mfma_f32_16x16x32_bf16(a, whf[kt][0], acc[0], 0, 0, 0);
            acc[0] = __builtin_amdgcn_mfma_f32_16x16x32_bf16(a, wlf[kt][0], acc[0], 0, 0, 0);
            acc[1] = __builtin_amdgcn_mfma_f32_16x16x32_bf16(a, whf[kt][1], acc[1], 0, 0, 0);
            acc[1] = __builtin_amdgcn_mfma_f32_16x16x32_bf16(a, wlf[kt][1], acc[1], 0, 0, 0);
        }

        // ---- adaptive-LIF update on the C/D fragment (exact ref rounding)
#pragma unroll
        for (int t = 0; t < 2; t++) {
#pragma unroll
            for (int j = 0; j < 4; j++) {
                const float dd = __fadd_rn(__fadd_rn(pv[t][j], acc[t][j]), brc_[t]);
                bbv[t][j] = __fadd_rn(__fmul_rn(ro_[t], bbv[t][j]),
                                      __fmul_rn(omR_[t], spkv[t][j]));
                const float thr = __fadd_rn(0.01f, __fmul_rn(1.8f, bbv[t][j]));
                mem[t][j] = __fsub_rn(
                    __fadd_rn(__fmul_rn(mem[t][j], alpha_[t]),
                              __fmul_rn(omA_[t], dd)),
                    __fmul_rn(thr, spkv[t][j]));
                const bool sp = __fsub_rn(mem[t][j], thr) > 0.f;
                spkv[t][j] = sp ? 1.f : 0.f;
                Sp[cur][l4 * 4 + j][w * 32 + t * 16 + l15] =
                    sp ? (ushort)0x3F80 : (ushort)0;
            }
        }

        // make own-wave spike writes visible to own-wave cross-lane reads
        asm volatile("s_waitcnt lgkmcnt(0)" ::: "memory");
        __builtin_amdgcn_sched_barrier(0);

        // ---- readout partial: this wave's 32-col k-slice of spk(cur)
        {
            const bf16x8 ar = *(const bf16x8*)&Sp[cur][l15][w * 32 + l4 * 8];
            f32x4 S0 = (f32x4){0.f, 0.f, 0.f, 0.f};
            f32x4 S1 = (f32x4){0.f, 0.f, 0.f, 0.f};
            S0 = __builtin_amdgcn_mfma_f32_16x16x32_bf16(ar, woh[0], S0, 0, 0, 0);
            S0 = __builtin_amdgcn_mfma_f32_16x16x32_bf16(ar, wol[0], S0, 0, 0, 0);
            S1 = __builtin_amdgcn_mfma_f32_16x16x32_bf16(ar, woh[1], S1, 0, 0, 0);
            S1 = __builtin_amdgcn_mfma_f32_16x16x32_bf16(ar, wol[1], S1, 0, 0, 0);
#pragma unroll
            for (int j = 0; j < 4; j++) {
                z[0][j] = __fmaf_rn(ao_[0], z[0][j], __fmul_rn(omo_[0], S0[j]));
                z[1][j] = __fmaf_rn(ao_[1], z[1][j], __fmul_rn(omo_[1], S1[j]));
            }
        }

#pragma unroll
        for (int t = 0; t < 2; t++)
#pragma unroll
            for (int j = 0; j < 4; j++) pv[t][j] = pv_next[t][j];
    }

    __syncthreads();   // all waves done reading P rows we now overwrite

    // ---- stash per-wave readout partials into consumed P rows
    float* stash = Pst + ((size_t)b0 * S_LEN) * 512 + d * HID;
#pragma unroll
    for (int j = 0; j < 4; j++) {
        const int r = l4 * 4 + j;
        const int idx0 = w * 320 + r * 16 + l15;
        stash[(size_t)(idx0 >> 8) * 512 + (idx0 & 255)] = z[0][j];
        if (l15 < 4) {
            const int idx1 = w * 320 + 256 + r * 4 + l15;
            stash[(size_t)(idx1 >> 8) * 512 + (idx1 & 255)] = z[1][j];
        }
    }
}

// ---------------------------------------------------------------------------
// Kernel 3: merge stashed partials + bias closed form + log_softmax.
// ---------------------------------------------------------------------------
__global__ __launch_bounds__(64) void merge_out(
    const float* __restrict__ Pst, const float* __restrict__ bout,
    const float* __restrict__ taumo, float* __restrict__ out)
{
    const int bb = blockIdx.x;
    const int o  = threadIdx.x;         // active 0..19
    const int g  = bb >> 4, r = bb & 15;

    float val = 0.f, v = -3.0e38f;
    if (o < OUT_N) {
        float tot = 0.f;
#pragma unroll
        for (int d2 = 0; d2 < 2; d2++) {
            const float* stash = Pst + ((size_t)(g * 16) * S_LEN) * 512 + d2 * HID;
#pragma unroll
            for (int w2 = 0; w2 < 8; w2++) {
                const int idx = (o < 16) ? (w2 * 320 + r * 16 + o)
                                         : (w2 * 320 + 256 + r * 4 + (o - 16));
                tot = __fadd_rn(tot, stash[(size_t)(idx >> 8) * 512 + (idx & 255)]);
            }
        }
        const float aS = expf(__fdiv_rn(-(float)S_LEN, taumo[o]));
        val = __fadd_rn(tot, __fmul_rn(bout[o], __fsub_rn(1.f, aS)));
        v = val;
    }
    float mx = v;
#pragma unroll
    for (int d2 = 1; d2 < 64; d2 <<= 1)
        mx = fmaxf(mx, __shfl_xor(mx, d2, 64));
    float e = (o < OUT_N) ? expf(__fsub_rn(val, mx)) : 0.f;
#pragma unroll
    for (int d2 = 1; d2 < 64; d2 <<= 1)
        e += __shfl_xor(e, d2, 64);
    if (o < OUT_N)
        out[(size_t)bb * OUT_N + o] =
            __fsub_rn(__fsub_rn(val, mx), logf(e));
}

// ---------------------------------------------------------------------------
extern "C" void kernel_launch(void* const* d_in, const int* in_sizes, int n_in,
                              void* d_out, int out_size, void* d_ws, size_t ws_size,
                              hipStream_t stream) {
    const float* x         = (const float*)d_in[0];
    const float* W_in_f    = (const float*)d_in[1];
    const float* b_in_f    = (const float*)d_in[2];
    const float* W_rec_f   = (const float*)d_in[3];
    const float* b_rec_f   = (const float*)d_in[4];
    const float* tau_m_f   = (const float*)d_in[5];
    const float* tau_adp_f = (const float*)d_in[6];
    const float* W_in_b    = (const float*)d_in[7];
    const float* b_in_b    = (const float*)d_in[8];
    const float* W_rec_b   = (const float*)d_in[9];
    const float* b_rec_b   = (const float*)d_in[10];
    const float* tau_m_b   = (const float*)d_in[11];
    const float* tau_adp_b = (const float*)d_in[12];
    const float* W_out     = (const float*)d_in[13];
    const float* b_out     = (const float*)d_in[14];
    const float* tau_m_o   = (const float*)d_in[15];
    float* out = (float*)d_out;
    float* P   = (float*)d_ws;

    const size_t needP = (size_t)BATCH * S_LEN * 512 * sizeof(float);
    const size_t planeW = (size_t)512 * KPAD;              // elements
    ushort* Wth = (ushort*)((char*)d_ws + needP);
    ushort* Wtl = Wth + planeW;
    const bool prew = (ws_size >= needP + 2 * planeW * sizeof(ushort));

    if (prew) {
        w_prep<<<dim3(KPAD), dim3(512), 0, stream>>>(W_in_f, W_in_b, Wth, Wtl);
        proj_mfma<true><<<dim3(2, 500), dim3(256), 0, stream>>>(
            x, W_in_f, W_in_b, b_in_f, b_in_b, Wth, Wtl, P);
    } else {
        proj_mfma<false><<<dim3(2, 500), dim3(256), 0, stream>>>(
            x, W_in_f, W_in_b, b_in_f, b_in_b, nullptr, nullptr, P);
    }
    scan_mfma<<<dim3(16, 2), dim3(512), 0, stream>>>(
        P, W_rec_f, b_rec_f, tau_m_f, tau_adp_f,
        W_rec_b, b_rec_b, tau_m_b, tau_adp_b,
        W_out, tau_m_o, P);
    merge_out<<<dim3(BATCH), dim3(64), 0, stream>>>(
        P, b_out, tau_m_o, out);
}

// Round 16
// 454.944 us; speedup vs baseline: 1.1041x; 1.1041x over previous
//
#include <hip/hip_runtime.h>
#include <cstdint>
#include <cstddef>

#define S_LEN 250
#define BATCH 256
#define CIN   700
#define HID   256
#define OUT_N 20
#define KSTEPS 22   // ceil(700/32)

typedef __attribute__((ext_vector_type(8))) short bf16x8;
typedef __attribute__((ext_vector_type(4))) float f32x4;

__device__ __forceinline__ ushort f2bf_rne(float f) {
    uint u = __float_as_uint(f);
    uint r = (u + 0x7FFFu + ((u >> 16) & 1u)) >> 16;
    return (ushort)r;
}
__device__ __forceinline__ float bf2f(ushort h) {
    return __uint_as_float(((uint)h) << 16);
}

// ---------------------------------------------------------------------------
// Kernel 1: input projection GEMM via bf16x3 split MFMA (R14 form — best
// measured: ~158us). One block per (direction, m-tile) = (2, 500); each block
// computes all 256 columns of one direction (x redundancy 2x, W once/block).
// In-loop hi/lo conversion with coalesced fp32 W reads (R15's prepped-W
// transpose regressed: same bytes, broken coalescing).
// ---------------------------------------------------------------------------
__global__ __launch_bounds__(256) void proj_mfma(
    const float* __restrict__ x,
    const float* __restrict__ Wf, const float* __restrict__ Wb,
    const float* __restrict__ biasf, const float* __restrict__ biasb,
    float* __restrict__ P)
{
    __shared__ ushort AsH[128][40];
    __shared__ ushort AsL[128][40];
    __shared__ ushort BsH[256][40];
    __shared__ ushort BsL[256][40];

    const int nt = blockIdx.x;          // 0 = fw cols, 1 = bw cols
    const int mt = blockIdx.y;          // 0..499
    const int m0 = mt * 128;
    const float* W   = nt ? Wb : Wf;
    const float* bia = nt ? biasb : biasf;

    const int tid  = threadIdx.x;
    const int lane = tid & 63;
    const int wv   = tid >> 6;          // wave 0..3
    const int wr   = wv >> 1;           // row-half
    const int wc   = wv & 1;            // col-half (128 cols each)
    const int l15  = lane & 15;
    const int l4   = lane >> 4;

    const int as  = tid & 7;            // A k-slot (4 floats)
    const int arr = tid >> 3;           // A row 0..31 (x4 row-groups)

    f32x4 acc[4][8];
#pragma unroll
    for (int i = 0; i < 4; i++)
#pragma unroll
        for (int j = 0; j < 8; j++)
            acc[i][j] = (f32x4){0.f, 0.f, 0.f, 0.f};

    float4 av[4];
    float bv[32];

#define PROJ_LOAD(K0_) do {                                                   \
        const int ka_ = (K0_) + as * 4;                                       \
        const bool aok_ = (ka_ + 3) < CIN;                                    \
        _Pragma("unroll")                                                     \
        for (int i_ = 0; i_ < 4; i_++) {                                      \
            av[i_] = make_float4(0.f, 0.f, 0.f, 0.f);                         \
            if (aok_)                                                         \
                av[i_] = *(const float4*)&x[(size_t)(m0 + arr + 32 * i_) * CIN + ka_]; \
        }                                                                     \
        _Pragma("unroll")                                                     \
        for (int j_ = 0; j_ < 32; j_++) {                                     \
            const int kb_ = (K0_) + j_;                                       \
            bv[j_] = (kb_ < CIN) ? W[(size_t)kb_ * HID + tid] : 0.f;          \
        }                                                                     \
    } while (0)

#define PROJ_CVT_WRITE() do {                                                 \
        _Pragma("unroll")                                                     \
        for (int i_ = 0; i_ < 4; i_++) {                                      \
            const int row_ = arr + 32 * i_;                                   \
            ushort4 h_, l_;                                                   \
            h_.x = f2bf_rne(av[i_].x); l_.x = f2bf_rne(__fsub_rn(av[i_].x, bf2f(h_.x))); \
            h_.y = f2bf_rne(av[i_].y); l_.y = f2bf_rne(__fsub_rn(av[i_].y, bf2f(h_.y))); \
            h_.z = f2bf_rne(av[i_].z); l_.z = f2bf_rne(__fsub_rn(av[i_].z, bf2f(h_.z))); \
            h_.w = f2bf_rne(av[i_].w); l_.w = f2bf_rne(__fsub_rn(av[i_].w, bf2f(h_.w))); \
            *(ushort4*)&AsH[row_][as * 4] = h_;                               \
            *(ushort4*)&AsL[row_][as * 4] = l_;                               \
        }                                                                     \
        _Pragma("unroll")                                                     \
        for (int q_ = 0; q_ < 8; q_++) {                                      \
            ushort4 h_, l_;                                                   \
            float v0_ = bv[q_ * 4 + 0], v1_ = bv[q_ * 4 + 1];                 \
            float v2_ = bv[q_ * 4 + 2], v3_ = bv[q_ * 4 + 3];                 \
            h_.x = f2bf_rne(v0_); l_.x = f2bf_rne(__fsub_rn(v0_, bf2f(h_.x))); \
            h_.y = f2bf_rne(v1_); l_.y = f2bf_rne(__fsub_rn(v1_, bf2f(h_.y))); \
            h_.z = f2bf_rne(v2_); l_.z = f2bf_rne(__fsub_rn(v2_, bf2f(h_.z))); \
            h_.w = f2bf_rne(v3_); l_.w = f2bf_rne(__fsub_rn(v3_, bf2f(h_.w))); \
            *(ushort4*)&BsH[tid][q_ * 4] = h_;                               \
            *(ushort4*)&BsL[tid][q_ * 4] = l_;                               \
        }                                                                     \
    } while (0)

    PROJ_LOAD(0);
    PROJ_CVT_WRITE();

    for (int kt = 0; kt < KSTEPS; kt++) {
        __syncthreads();                 // tile kt writes visible
        if (kt + 1 < KSTEPS)
            PROJ_LOAD((kt + 1) * 32);    // next loads land during MFMA

#pragma unroll
        for (int fc = 0; fc < 8; fc++) {
            const bf16x8 bHf = *(const bf16x8*)&BsH[wc * 128 + fc * 16 + l15][l4 * 8];
            const bf16x8 bLf = *(const bf16x8*)&BsL[wc * 128 + fc * 16 + l15][l4 * 8];
#pragma unroll
            for (int fr = 0; fr < 4; fr++) {
                const bf16x8 aHf = *(const bf16x8*)&AsH[wr * 64 + fr * 16 + l15][l4 * 8];
                const bf16x8 aLf = *(const bf16x8*)&AsL[wr * 64 + fr * 16 + l15][l4 * 8];
                acc[fr][fc] = __builtin_amdgcn_mfma_f32_16x16x32_bf16(
                    aHf, bHf, acc[fr][fc], 0, 0, 0);
                acc[fr][fc] = __builtin_amdgcn_mfma_f32_16x16x32_bf16(
                    aHf, bLf, acc[fr][fc], 0, 0, 0);
                acc[fr][fc] = __builtin_amdgcn_mfma_f32_16x16x32_bf16(
                    aLf, bHf, acc[fr][fc], 0, 0, 0);
            }
        }

        __syncthreads();                 // all reads of tile kt done
        if (kt + 1 < KSTEPS)
            PROJ_CVT_WRITE();
    }

#undef PROJ_LOAD
#undef PROJ_CVT_WRITE

#pragma unroll
    for (int fc = 0; fc < 8; fc++) {
        const int col = wc * 128 + fc * 16 + l15;      // 0..255 in direction
        const float bvs = bia[col];
#pragma unroll
        for (int fr = 0; fr < 4; fr++) {
#pragma unroll
            for (int j = 0; j < 4; j++) {
                const int row = m0 + wr * 64 + fr * 16 + l4 * 4 + j;
                P[(size_t)row * 512 + nt * HID + col] =
                    __fadd_rn(acc[fr][fc][j], bvs);
            }
        }
    }
}

// ---------------------------------------------------------------------------
// Kernel 2: MFMA scan — EXACT R6 form (best measured: 293-294us, absmax
// 0.0625). All timing micro-variants (R7/R9/R10/R13) measured neutral or
// worse; active-CU counters show ~76% MFMA+VALU issue-busy = structural
// optimum for this decomposition. FROZEN.
// ---------------------------------------------------------------------------
__global__ __launch_bounds__(512, 2) void scan_mfma(
    const float* __restrict__ P,
    const float* __restrict__ Wrecf, const float* __restrict__ brecf,
    const float* __restrict__ taumf, const float* __restrict__ tauaf,
    const float* __restrict__ Wrecb, const float* __restrict__ brecb,
    const float* __restrict__ taumb, const float* __restrict__ tauab,
    const float* __restrict__ Wout, const float* __restrict__ taumo,
    float* __restrict__ Pst)
{
    const int g  = blockIdx.x;          // batch group: b0..b0+15
    const int d  = blockIdx.y;          // 0 = fw, 1 = bw
    const int b0 = g * 16;
    const bool fw = (d == 0);

    const int tid  = threadIdx.x;
    const int lane = tid & 63;
    const int w    = tid >> 6;          // wave 0..7
    const int l15  = lane & 15;
    const int l4   = lane >> 4;

    __shared__ ushort Sp[2][16][264];   // [buf][batch][col(+pad)] bf16 spikes

    {   // zero both spike buffers (step -1 spikes = 0)
        ushort* p = &Sp[0][0][0];
        for (int i = tid; i < 2 * 16 * 264; i += 512) p[i] = 0;
    }

    const float* Wrec = fw ? Wrecf : Wrecb;

    // ---- W_rec fragments (hi+lo bf16), register resident
    bf16x8 whf[8][2], wlf[8][2];
#pragma unroll
    for (int kt = 0; kt < 8; kt++)
#pragma unroll
        for (int ct = 0; ct < 2; ct++) {
            const int c = w * 32 + ct * 16 + l15;
#pragma unroll
            for (int j = 0; j < 8; j++) {
                const float v = Wrec[(size_t)(kt * 32 + l4 * 8 + j) * HID + c];
                const ushort h = f2bf_rne(v);
                const ushort l = f2bf_rne(__fsub_rn(v, bf2f(h)));
                whf[kt][ct][j] = (short)h;
                wlf[kt][ct][j] = (short)l;
            }
        }

    // ---- W_out fragments for this wave's 32-k slice (hi+lo)
    bf16x8 woh[2], wol[2];
#pragma unroll
    for (int t = 0; t < 2; t++) {
        const int o = t * 16 + l15;
#pragma unroll
        for (int j = 0; j < 8; j++) {
            float v = 0.f;
            if (o < OUT_N)
                v = Wout[(size_t)(d * HID + w * 32 + l4 * 8 + j) * OUT_N + o];
            const ushort h = f2bf_rne(v);
            const ushort l = f2bf_rne(__fsub_rn(v, bf2f(h)));
            woh[t][j] = (short)h;
            wol[t][j] = (short)l;
        }
    }

    // ---- LIF constants for this thread's 2 columns
    float alpha_[2], ro_[2], omA_[2], omR_[2], brc_[2];
#pragma unroll
    for (int t = 0; t < 2; t++) {
        const int c = w * 32 + t * 16 + l15;
        alpha_[t] = expf(__fdiv_rn(-1.f, fw ? taumf[c] : taumb[c]));
        ro_[t]    = expf(__fdiv_rn(-1.f, fw ? tauaf[c] : tauab[c]));
        omA_[t]   = __fsub_rn(1.f, alpha_[t]);
        omR_[t]   = __fsub_rn(1.f, ro_[t]);
        brc_[t]   = fw ? brecf[c] : brecb[c];
    }
    // ---- readout constants
    float ao_[2], omo_[2];
#pragma unroll
    for (int t = 0; t < 2; t++) {
        const int o = t * 16 + l15;
        if (o < OUT_N) {
            ao_[t]  = expf(__fdiv_rn(-1.f, taumo[o]));
            omo_[t] = __fsub_rn(1.f, ao_[t]);
        } else { ao_[t] = 0.f; omo_[t] = 0.f; }
    }

    float mem[2][4], bbv[2][4], spkv[2][4], z[2][4];
#pragma unroll
    for (int t = 0; t < 2; t++)
#pragma unroll
        for (int j = 0; j < 4; j++) {
            mem[t][j] = 0.f; bbv[t][j] = 0.01f; spkv[t][j] = 0.f; z[t][j] = 0.f;
        }

    // pv prefetch for s=0
    float pv[2][4];
    {
        const int srow = fw ? 0 : (S_LEN - 1);
#pragma unroll
        for (int t = 0; t < 2; t++)
#pragma unroll
            for (int j = 0; j < 4; j++)
                pv[t][j] = P[((size_t)(b0 + l4 * 4 + j) * S_LEN + srow) * 512
                             + d * HID + w * 32 + t * 16 + l15];
    }

    for (int s = 0; s < S_LEN; s++) {
        const int cur = s & 1, prev = cur ^ 1;

        // prefetch next step's projection BEFORE the barrier (R6 exact)
        float pv_next[2][4];
        {
            const int sn   = (s + 1 < S_LEN) ? s + 1 : S_LEN - 1;
            const int srow = fw ? sn : (S_LEN - 1 - sn);
#pragma unroll
            for (int t = 0; t < 2; t++)
#pragma unroll
                for (int j = 0; j < 4; j++)
                    pv_next[t][j] = P[((size_t)(b0 + l4 * 4 + j) * S_LEN + srow) * 512
                                      + d * HID + w * 32 + t * 16 + l15];
        }

        __syncthreads();   // Sp[prev] complete from all waves

        // ---- recurrent GEMM: D[batch][col] += spk(prev) @ W_rec
        f32x4 acc[2];
        acc[0] = (f32x4){0.f, 0.f, 0.f, 0.f};
        acc[1] = (f32x4){0.f, 0.f, 0.f, 0.f};
#pragma unroll
        for (int kt = 0; kt < 8; kt++) {
            const bf16x8 a = *(const bf16x8*)&Sp[prev][l15][kt * 32 + l4 * 8];
            acc[0] = __builtin_amdgcn_mfma_f32_16x16x32_bf16(a, whf[kt][0], acc[0], 0, 0, 0);
            acc[0] = __builtin_amdgcn_mfma_f32_16x16x32_bf16(a, wlf[kt][0], acc[0], 0, 0, 0);
            acc[1] = __builtin_amdgcn_mfma_f32_16x16x32_bf16(a, whf[kt][1], acc[1], 0, 0, 0);
            acc[1] = __builtin_amdgcn_mfma_f32_16x16x32_bf16(a, wlf[kt][1], acc[1], 0, 0, 0);
        }

        // ---- adaptive-LIF update on the C/D fragment (exact ref rounding)
#pragma unroll
        for (int t = 0; t < 2; t++) {
#pragma unroll
            for (int j = 0; j < 4; j++) {
                const float dd = __fadd_rn(__fadd_rn(pv[t][j], acc[t][j]), brc_[t]);
                bbv[t][j] = __fadd_rn(__fmul_rn(ro_[t], bbv[t][j]),
                                      __fmul_rn(omR_[t], spkv[t][j]));
                const float thr = __fadd_rn(0.01f, __fmul_rn(1.8f, bbv[t][j]));
                mem[t][j] = __fsub_rn(
                    __fadd_rn(__fmul_rn(mem[t][j], alpha_[t]),
                              __fmul_rn(omA_[t], dd)),
                    __fmul_rn(thr, spkv[t][j]));
                const bool sp = __fsub_rn(mem[t][j], thr) > 0.f;
                spkv[t][j] = sp ? 1.f : 0.f;
                Sp[cur][l4 * 4 + j][w * 32 + t * 16 + l15] =
                    sp ? (ushort)0x3F80 : (ushort)0;
            }
        }

        // make own-wave spike writes visible to own-wave cross-lane reads
        asm volatile("s_waitcnt lgkmcnt(0)" ::: "memory");
        __builtin_amdgcn_sched_barrier(0);

        // ---- readout partial: this wave's 32-col k-slice of spk(cur)
        {
            const bf16x8 ar = *(const bf16x8*)&Sp[cur][l15][w * 32 + l4 * 8];
            f32x4 S0 = (f32x4){0.f, 0.f, 0.f, 0.f};
            f32x4 S1 = (f32x4){0.f, 0.f, 0.f, 0.f};
            S0 = __builtin_amdgcn_mfma_f32_16x16x32_bf16(ar, woh[0], S0, 0, 0, 0);
            S0 = __builtin_amdgcn_mfma_f32_16x16x32_bf16(ar, wol[0], S0, 0, 0, 0);
            S1 = __builtin_amdgcn_mfma_f32_16x16x32_bf16(ar, woh[1], S1, 0, 0, 0);
            S1 = __builtin_amdgcn_mfma_f32_16x16x32_bf16(ar, wol[1], S1, 0, 0, 0);
#pragma unroll
            for (int j = 0; j < 4; j++) {
                z[0][j] = __fmaf_rn(ao_[0], z[0][j], __fmul_rn(omo_[0], S0[j]));
                z[1][j] = __fmaf_rn(ao_[1], z[1][j], __fmul_rn(omo_[1], S1[j]));
            }
        }

#pragma unroll
        for (int t = 0; t < 2; t++)
#pragma unroll
            for (int j = 0; j < 4; j++) pv[t][j] = pv_next[t][j];
    }

    __syncthreads();   // all waves done reading P rows we now overwrite

    // ---- stash per-wave readout partials into consumed P rows
    float* stash = Pst + ((size_t)b0 * S_LEN) * 512 + d * HID;
#pragma unroll
    for (int j = 0; j < 4; j++) {
        const int r = l4 * 4 + j;
        const int idx0 = w * 320 + r * 16 + l15;
        stash[(size_t)(idx0 >> 8) * 512 + (idx0 & 255)] = z[0][j];
        if (l15 < 4) {
            const int idx1 = w * 320 + 256 + r * 4 + l15;
            stash[(size_t)(idx1 >> 8) * 512 + (idx1 & 255)] = z[1][j];
        }
    }
}

// ---------------------------------------------------------------------------
// Kernel 3: merge stashed partials + bias closed form + log_softmax.
// ---------------------------------------------------------------------------
__global__ __launch_bounds__(64) void merge_out(
    const float* __restrict__ Pst, const float* __restrict__ bout,
    const float* __restrict__ taumo, float* __restrict__ out)
{
    const int bb = blockIdx.x;
    const int o  = threadIdx.x;         // active 0..19
    const int g  = bb >> 4, r = bb & 15;

    float val = 0.f, v = -3.0e38f;
    if (o < OUT_N) {
        float tot = 0.f;
#pragma unroll
        for (int d2 = 0; d2 < 2; d2++) {
            const float* stash = Pst + ((size_t)(g * 16) * S_LEN) * 512 + d2 * HID;
#pragma unroll
            for (int w2 = 0; w2 < 8; w2++) {
                const int idx = (o < 16) ? (w2 * 320 + r * 16 + o)
                                         : (w2 * 320 + 256 + r * 4 + (o - 16));
                tot = __fadd_rn(tot, stash[(size_t)(idx >> 8) * 512 + (idx & 255)]);
            }
        }
        const float aS = expf(__fdiv_rn(-(float)S_LEN, taumo[o]));
        val = __fadd_rn(tot, __fmul_rn(bout[o], __fsub_rn(1.f, aS)));
        v = val;
    }
    float mx = v;
#pragma unroll
    for (int d2 = 1; d2 < 64; d2 <<= 1)
        mx = fmaxf(mx, __shfl_xor(mx, d2, 64));
    float e = (o < OUT_N) ? expf(__fsub_rn(val, mx)) : 0.f;
#pragma unroll
    for (int d2 = 1; d2 < 64; d2 <<= 1)
        e += __shfl_xor(e, d2, 64);
    if (o < OUT_N)
        out[(size_t)bb * OUT_N + o] =
            __fsub_rn(__fsub_rn(val, mx), logf(e));
}

// ---------------------------------------------------------------------------
extern "C" void kernel_launch(void* const* d_in, const int* in_sizes, int n_in,
                              void* d_out, int out_size, void* d_ws, size_t ws_size,
                              hipStream_t stream) {
    const float* x         = (const float*)d_in[0];
    const float* W_in_f    = (const float*)d_in[1];
    const float* b_in_f    = (const float*)d_in[2];
    const float* W_rec_f   = (const float*)d_in[3];
    const float* b_rec_f   = (const float*)d_in[4];
    const float* tau_m_f   = (const float*)d_in[5];
    const float* tau_adp_f = (const float*)d_in[6];
    const float* W_in_b    = (const float*)d_in[7];
    const float* b_in_b    = (const float*)d_in[8];
    const float* W_rec_b   = (const float*)d_in[9];
    const float* b_rec_b   = (const float*)d_in[10];
    const float* tau_m_b   = (const float*)d_in[11];
    const float* tau_adp_b = (const float*)d_in[12];
    const float* W_out     = (const float*)d_in[13];
    const float* b_out     = (const float*)d_in[14];
    const float* tau_m_o   = (const float*)d_in[15];
    float* out = (float*)d_out;
    float* P   = (float*)d_ws;

    proj_mfma<<<dim3(2, 500), dim3(256), 0, stream>>>(
        x, W_in_f, W_in_b, b_in_f, b_in_b, P);
    scan_mfma<<<dim3(16, 2), dim3(512), 0, stream>>>(
        P, W_rec_f, b_rec_f, tau_m_f, tau_adp_f,
        W_rec_b, b_rec_b, tau_m_b, tau_adp_b,
        W_out, tau_m_o, P);
    merge_out<<<dim3(BATCH), dim3(64), 0, stream>>>(
        P, b_out, tau_m_o, out);
}